// Round 1
// baseline (516.675 us; speedup 1.0000x reference)
//
#include <hip/hip_runtime.h>
#include <math.h>

#define NROWS   16384
#define IN_DIM  64
#define HID     256
#define OUT_DIM 64
#define NEXP    256
#define MT      16
#define SLICES  4

// ---------------- bucketing kernels ----------------

__global__ void count_k(const int* __restrict__ ind, int* __restrict__ counts) {
  int n = blockIdx.x * 256 + threadIdx.x;
  if (n < NROWS) atomicAdd(&counts[ind[n]], 1);
}

__global__ void scan_k(const int* __restrict__ counts, int* __restrict__ offsets,
                       int* __restrict__ cursor) {
  __shared__ int s[NEXP];
  int t = threadIdx.x;
  int c = counts[t];
  s[t] = c;
  __syncthreads();
  for (int d = 1; d < NEXP; d <<= 1) {
    int v = (t >= d) ? s[t - d] : 0;
    __syncthreads();
    s[t] += v;
    __syncthreads();
  }
  int exc = s[t] - c;           // exclusive prefix
  offsets[t] = exc;
  cursor[t]  = exc;
  if (t == NEXP - 1) offsets[NEXP] = s[t];
}

__global__ void scatter_k(const int* __restrict__ ind, int* __restrict__ cursor,
                          int* __restrict__ rows) {
  int n = blockIdx.x * 256 + threadIdx.x;
  if (n < NROWS) {
    int p = atomicAdd(&cursor[ind[n]], 1);
    rows[p] = n;
  }
}

// ---------------- main MLP kernel ----------------

__device__ __forceinline__ float dot16(const float4 w0, const float4 w1,
                                       const float4 w2, const float4 w3,
                                       const float* __restrict__ ip) {
  float4 x0 = *(const float4*)(ip);
  float4 x1 = *(const float4*)(ip + 4);
  float4 x2 = *(const float4*)(ip + 8);
  float4 x3 = *(const float4*)(ip + 12);
  return w0.x * x0.x + w0.y * x0.y + w0.z * x0.z + w0.w * x0.w
       + w1.x * x1.x + w1.y * x1.y + w1.z * x1.z + w1.w * x1.w
       + w2.x * x2.x + w2.y * x2.y + w2.z * x2.z + w2.w * x2.w
       + w3.x * x3.x + w3.y * x3.y + w3.z * x3.z + w3.w * x3.w;
}

// One wide layer (O=256 outputs, thread t owns output t), K in {64,256}.
// in: [MT][HID] LDS buffer (only first K cols used), out: [MT][HID] LDS buffer.
template <int K, bool DO_TANH>
__device__ __forceinline__ void layer_wide(const float* __restrict__ We, float bv,
                                           const float (*in)[HID], float (*outBuf)[HID],
                                           float* __restrict__ sW, int t) {
  float acc[MT];
#pragma unroll
  for (int m = 0; m < MT; m++) acc[m] = bv;
  for (int kc = 0; kc < K; kc += 16) {
    __syncthreads();  // previous consumers of sW done
#pragma unroll
    for (int i = 0; i < 4; i++) {
      int flat = t * 4 + i * 1024;          // 4096 floats = 256 outs x 16 ks
      int o = flat >> 4, j = flat & 15;
      *(float4*)&sW[flat] = *(const float4*)&We[o * K + kc + j];
    }
    __syncthreads();
    float4 w0 = *(float4*)&sW[t * 16 + 0];
    float4 w1 = *(float4*)&sW[t * 16 + 4];
    float4 w2 = *(float4*)&sW[t * 16 + 8];
    float4 w3 = *(float4*)&sW[t * 16 + 12];
#pragma unroll
    for (int m = 0; m < MT; m++) acc[m] += dot16(w0, w1, w2, w3, &in[m][kc]);
  }
#pragma unroll
  for (int m = 0; m < MT; m++) {
    float v = acc[m];
    outBuf[m][t] = DO_TANH ? tanhf(v) : v;
  }
}

__global__ __launch_bounds__(256, 3) void mlp_k(
    const float* __restrict__ x,
    const float* __restrict__ W1, const float* __restrict__ b1,
    const float* __restrict__ W2, const float* __restrict__ b2,
    const float* __restrict__ Wl, const float* __restrict__ bl,
    const int* __restrict__ rows, const int* __restrict__ offsets,
    float* __restrict__ out) {
  const int t = threadIdx.x;
  const int e = blockIdx.x >> 2;           // expert
  const int s = blockIdx.x & (SLICES - 1); // slice within expert
  const int beg = offsets[e];
  const int cnt = offsets[e + 1] - beg;

  __shared__ float sW[HID * 16];   // 16 KB weight chunk
  __shared__ float sA[MT][HID];    // 16 KB (x tile, then h2)
  __shared__ float sB[MT][HID];    // 16 KB (h1)

  const float* W1e = W1 + (size_t)e * HID * IN_DIM;
  const float* W2e = W2 + (size_t)e * HID * HID;
  const float* Wle = Wl + (size_t)e * OUT_DIM * HID;
  const float b1v = b1[e * HID + t];
  const float b2v = b2[e * HID + t];
  const int o3 = t & 63, g3 = t >> 6;
  const float blv = bl[e * OUT_DIM + o3];

  for (int mt0 = s * MT; mt0 < cnt; mt0 += SLICES * MT) {
    __syncthreads();  // prev tile's layer3 done reading sA
    // ---- stage x tile into sA[.][0..63] (zero-padded for invalid rows)
    {
      int m = t >> 4, c = (t & 15) << 2;
      int gm = mt0 + m;
      float4 v = make_float4(0.f, 0.f, 0.f, 0.f);
      if (gm < cnt) {
        int r = rows[beg + gm];
        v = *(const float4*)&x[r * IN_DIM + c];
      }
      *(float4*)&sA[m][c] = v;
    }
    // (visibility of sA ensured by the two syncs inside layer_wide's first chunk)

    // ---- layer1: sA(K=64) -> sB(O=256), tanh
    layer_wide<IN_DIM, true>(W1e, b1v, sA, sB, sW, t);
    // ---- layer2: sB(K=256) -> sA(O=256), tanh
    layer_wide<HID, true>(W2e, b2v, sB, sA, sW, t);

    // ---- layer3: sA(K=256) -> out (O=64). group g3 handles rows 4*g3..4*g3+3
    {
      float acc[4];
#pragma unroll
      for (int i = 0; i < 4; i++) acc[i] = blv;
      for (int kc = 0; kc < HID; kc += 16) {
        __syncthreads();
        {
          int flat = t * 4;                       // 1024 floats = 64 outs x 16 ks
          int o = flat >> 4, j = flat & 15;
          *(float4*)&sW[flat] = *(const float4*)&Wle[o * HID + kc + j];
        }
        __syncthreads();
        float4 w0 = *(float4*)&sW[o3 * 16 + 0];
        float4 w1 = *(float4*)&sW[o3 * 16 + 4];
        float4 w2 = *(float4*)&sW[o3 * 16 + 8];
        float4 w3 = *(float4*)&sW[o3 * 16 + 12];
#pragma unroll
        for (int mi = 0; mi < 4; mi++) {
          int m = g3 * 4 + mi;
          acc[mi] += dot16(w0, w1, w2, w3, &sA[m][kc]);
        }
      }
#pragma unroll
      for (int mi = 0; mi < 4; mi++) {
        int gm = mt0 + g3 * 4 + mi;
        if (gm < cnt) {
          int r = rows[beg + gm];
          out[r * OUT_DIM + o3] = acc[mi];
        }
      }
    }
  }
}

// ---------------- launcher ----------------

extern "C" void kernel_launch(void* const* d_in, const int* in_sizes, int n_in,
                              void* d_out, int out_size, void* d_ws, size_t ws_size,
                              hipStream_t stream) {
  const float* x   = (const float*)d_in[0];
  const int*   ind = (const int*)d_in[1];
  const float* W1  = (const float*)d_in[2];
  const float* b1  = (const float*)d_in[3];
  const float* W2  = (const float*)d_in[4];
  const float* b2  = (const float*)d_in[5];
  const float* Wl  = (const float*)d_in[6];
  const float* bl  = (const float*)d_in[7];
  float* out = (float*)d_out;

  int* wsi     = (int*)d_ws;
  int* counts  = wsi;          // 256 ints
  int* offsets = wsi + 256;    // 257 ints
  int* cursor  = wsi + 520;    // 256 ints
  int* rows    = wsi + 1024;   // 16384 ints

  hipMemsetAsync(counts, 0, 256 * sizeof(int), stream);
  count_k<<<NROWS / 256, 256, 0, stream>>>(ind, counts);
  scan_k<<<1, NEXP, 0, stream>>>(counts, offsets, cursor);
  scatter_k<<<NROWS / 256, 256, 0, stream>>>(ind, cursor, rows);
  mlp_k<<<NEXP * SLICES, 256, 0, stream>>>(x, W1, b1, W2, b2, Wl, bl, rows, offsets, out);
}

// Round 2
// 301.664 us; speedup vs baseline: 1.7128x; 1.7128x over previous
//
#include <hip/hip_runtime.h>
#include <math.h>

#define NROWS   16384
#define IN_DIM  64
#define HID     256
#define OUT_DIM 64
#define NEXP    256
#define MT      64          // rows per tile (block)

// ---------------- fused bucketing kernel (single block) ----------------

__global__ __launch_bounds__(1024) void prep_k(const int* __restrict__ ind,
                                               int* __restrict__ rows,
                                               int* __restrict__ offsets) {
  __shared__ int hist[NEXP];
  __shared__ int scan[NEXP];
  __shared__ int cur[NEXP];
  int t = threadIdx.x;
  if (t < NEXP) hist[t] = 0;
  __syncthreads();
  for (int n = t; n < NROWS; n += 1024) atomicAdd(&hist[ind[n]], 1);
  __syncthreads();
  if (t < NEXP) scan[t] = hist[t];
  __syncthreads();
  for (int d = 1; d < NEXP; d <<= 1) {
    int v = (t < NEXP && t >= d) ? scan[t - d] : 0;
    __syncthreads();
    if (t < NEXP) scan[t] += v;
    __syncthreads();
  }
  if (t < NEXP) {
    int exc = scan[t] - hist[t];
    offsets[t] = exc;
    cur[t] = exc;
    if (t == NEXP - 1) offsets[NEXP] = scan[t];
  }
  __syncthreads();
  for (int n = t; n < NROWS; n += 1024) {
    int p = atomicAdd(&cur[ind[n]], 1);
    rows[p] = n;
  }
}

// ---------------- main MLP kernel ----------------

__device__ __forceinline__ float fast_tanh(float v) {
  float e = __expf(2.f * v);
  return 1.f - 2.f * __builtin_amdgcn_rcpf(e + 1.f);
}

__device__ __forceinline__ float dot4(float4 w, float4 h, float a) {
  a = fmaf(w.x, h.x, a);
  a = fmaf(w.y, h.y, a);
  a = fmaf(w.z, h.z, a);
  a = fmaf(w.w, h.w, a);
  return a;
}

// Fragment matmul: this thread owns 4 output neurons (weight rows Wr[0..3],
// row-major, K wide) x NR input rows (hbase, stride 256 floats). Weights come
// straight from global, double-buffered in registers, 8-k chunks. Activation
// reads are LDS b128 (wave-uniform broadcast for layers 1/2).
template <int K, int NR>
__device__ __forceinline__ void frag_mm(const float* __restrict__ w0,
                                        const float* __restrict__ w1,
                                        const float* __restrict__ w2,
                                        const float* __restrict__ w3,
                                        const float* __restrict__ hbase,
                                        float (&acc)[4][NR]) {
  const float* Wr[4] = {w0, w1, w2, w3};
  float4 wA[4][2], wB[4][2];
#pragma unroll
  for (int n = 0; n < 4; n++) {
    wA[n][0] = *(const float4*)(Wr[n] + 0);
    wA[n][1] = *(const float4*)(Wr[n] + 4);
  }
  for (int kc = 0; kc < K; kc += 16) {
    // prefetch k-chunk kc+8
#pragma unroll
    for (int n = 0; n < 4; n++) {
      wB[n][0] = *(const float4*)(Wr[n] + kc + 8);
      wB[n][1] = *(const float4*)(Wr[n] + kc + 12);
    }
    // compute chunk kc with wA
#pragma unroll
    for (int m = 0; m < NR; m++) {
      const float* hp = hbase + m * HID + kc;
      float4 h0 = *(const float4*)(hp);
      float4 h1 = *(const float4*)(hp + 4);
#pragma unroll
      for (int n = 0; n < 4; n++) {
        float a = acc[n][m];
        a = dot4(wA[n][0], h0, a);
        a = dot4(wA[n][1], h1, a);
        acc[n][m] = a;
      }
    }
    // prefetch k-chunk kc+16 (guard: dummy re-read of k=0 on last iter)
    int kn = (kc + 16 < K) ? kc + 16 : 0;
#pragma unroll
    for (int n = 0; n < 4; n++) {
      wA[n][0] = *(const float4*)(Wr[n] + kn);
      wA[n][1] = *(const float4*)(Wr[n] + kn + 4);
    }
    // compute chunk kc+8 with wB
#pragma unroll
    for (int m = 0; m < NR; m++) {
      const float* hp = hbase + m * HID + kc + 8;
      float4 h0 = *(const float4*)(hp);
      float4 h1 = *(const float4*)(hp + 4);
#pragma unroll
      for (int n = 0; n < 4; n++) {
        float a = acc[n][m];
        a = dot4(wB[n][0], h0, a);
        a = dot4(wB[n][1], h1, a);
        acc[n][m] = a;
      }
    }
  }
}

__global__ __launch_bounds__(256, 2) void mlp_k(
    const float* __restrict__ x,
    const float* __restrict__ W1, const float* __restrict__ b1,
    const float* __restrict__ W2, const float* __restrict__ b2,
    const float* __restrict__ Wl, const float* __restrict__ bl,
    const int* __restrict__ rows, const int* __restrict__ offsets,
    float* __restrict__ out) {
  // H holds activations: x tile aliased into H[m][192..256) (dead before h1
  // writes), then h1 (overwritten by h2) across the full [64][256].
  __shared__ float H[MT * HID];  // 64 KB -> 2 blocks/CU

  const int t = threadIdx.x;
  const int e = blockIdx.x >> 1;   // expert
  const int j = blockIdx.x & 1;    // 0: tile 0; 1: tiles 1,2,...
  const int beg = offsets[e];
  const int cnt = offsets[e + 1] - beg;

  // layers 1/2 mapping: 4 neurons x 16 rows, rows wave-uniform
  const int n0 = 4 * (t & 63);
  const int m0 = 16 * (t >> 6);
  // layer 3 mapping: 4 neurons x 4 rows
  const int n3 = 4 * (t & 15);
  const int m3 = 4 * (t >> 4);
  // x staging mapping: 4 threads per row
  const int sm = t >> 2;
  const int sc = (t & 3) * 16;

  const float* W1e = W1 + (size_t)e * HID * IN_DIM;
  const float* W2e = W2 + (size_t)e * HID * HID;
  const float* Wle = Wl + (size_t)e * OUT_DIM * HID;
  const float4 b1v = *(const float4*)(b1 + e * HID + n0);
  const float4 b2v = *(const float4*)(b2 + e * HID + n0);
  const float4 blv = *(const float4*)(bl + e * OUT_DIM + n3);

  int mt0 = j * MT;
  while (mt0 < cnt) {
    __syncthreads();  // prev tile's layer3 done reading H
    // ---- stage x tile into H[m][192..256), zero-padded
    {
      int gm = mt0 + sm;
      bool val = gm < cnt;
      int r = val ? rows[beg + gm] : 0;
      const float* xr = x + (size_t)r * IN_DIM + sc;
      float* hx = &H[sm * HID + 192 + sc];
#pragma unroll
      for (int q = 0; q < 4; q++) {
        float4 v = val ? *(const float4*)(xr + 4 * q)
                       : make_float4(0.f, 0.f, 0.f, 0.f);
        *(float4*)(hx + 4 * q) = v;
      }
    }
    __syncthreads();

    // ---- layer1: x(K=64) -> h1(256), tanh
    {
      float acc[4][16];
#pragma unroll
      for (int m = 0; m < 16; m++) {
        acc[0][m] = b1v.x; acc[1][m] = b1v.y;
        acc[2][m] = b1v.z; acc[3][m] = b1v.w;
      }
      frag_mm<IN_DIM, 16>(W1e + (n0 + 0) * IN_DIM, W1e + (n0 + 1) * IN_DIM,
                          W1e + (n0 + 2) * IN_DIM, W1e + (n0 + 3) * IN_DIM,
                          &H[m0 * HID + 192], acc);
      __syncthreads();  // all x reads done before h1 writes clobber H
#pragma unroll
      for (int m = 0; m < 16; m++) {
        float4 v = make_float4(fast_tanh(acc[0][m]), fast_tanh(acc[1][m]),
                               fast_tanh(acc[2][m]), fast_tanh(acc[3][m]));
        *(float4*)&H[(m0 + m) * HID + n0] = v;
      }
    }
    __syncthreads();

    // ---- layer2: h1(K=256) -> h2(256), tanh (h2 overwrites h1)
    {
      float acc[4][16];
#pragma unroll
      for (int m = 0; m < 16; m++) {
        acc[0][m] = b2v.x; acc[1][m] = b2v.y;
        acc[2][m] = b2v.z; acc[3][m] = b2v.w;
      }
      frag_mm<HID, 16>(W2e + (n0 + 0) * HID, W2e + (n0 + 1) * HID,
                       W2e + (n0 + 2) * HID, W2e + (n0 + 3) * HID,
                       &H[m0 * HID], acc);
      __syncthreads();  // all h1 reads done before h2 writes
#pragma unroll
      for (int m = 0; m < 16; m++) {
        float4 v = make_float4(fast_tanh(acc[0][m]), fast_tanh(acc[1][m]),
                               fast_tanh(acc[2][m]), fast_tanh(acc[3][m]));
        *(float4*)&H[(m0 + m) * HID + n0] = v;
      }
    }
    __syncthreads();

    // ---- layer3: h2(K=256) -> out(64)
    {
      float acc[4][4];
#pragma unroll
      for (int m = 0; m < 4; m++) {
        acc[0][m] = blv.x; acc[1][m] = blv.y;
        acc[2][m] = blv.z; acc[3][m] = blv.w;
      }
      frag_mm<HID, 4>(Wle + (n3 + 0) * HID, Wle + (n3 + 1) * HID,
                      Wle + (n3 + 2) * HID, Wle + (n3 + 3) * HID,
                      &H[m3 * HID], acc);
#pragma unroll
      for (int m = 0; m < 4; m++) {
        int gm = mt0 + m3 + m;
        if (gm < cnt) {
          int r = rows[beg + gm];
          float4 v = make_float4(acc[0][m], acc[1][m], acc[2][m], acc[3][m]);
          *(float4*)(out + (size_t)r * OUT_DIM + n3) = v;
        }
      }
    }

    if (!j) break;
    mt0 += MT;
  }
}

// ---------------- launcher ----------------

extern "C" void kernel_launch(void* const* d_in, const int* in_sizes, int n_in,
                              void* d_out, int out_size, void* d_ws, size_t ws_size,
                              hipStream_t stream) {
  const float* x   = (const float*)d_in[0];
  const int*   ind = (const int*)d_in[1];
  const float* W1  = (const float*)d_in[2];
  const float* b1  = (const float*)d_in[3];
  const float* W2  = (const float*)d_in[4];
  const float* b2  = (const float*)d_in[5];
  const float* Wl  = (const float*)d_in[6];
  const float* bl  = (const float*)d_in[7];
  float* out = (float*)d_out;

  int* offsets = (int*)d_ws;        // 257 ints
  int* rows    = (int*)d_ws + 260;  // 16384 ints

  prep_k<<<1, 1024, 0, stream>>>(ind, rows, offsets);
  mlp_k<<<NEXP * 2, 256, 0, stream>>>(x, W1, b1, W2, b2, Wl, bl, rows, offsets, out);
}

// Round 4
// 170.747 us; speedup vs baseline: 3.0260x; 1.7667x over previous
//
#include <hip/hip_runtime.h>
#include <math.h>

#define NROWS   16384
#define IN_DIM  64
#define HID     256
#define OUT_DIM 64
#define NEXP    256
#define MT      64     // rows per tile
#define HP      264    // padded LDS row stride (bf16 elems): 528 B, 16B-aligned

typedef __attribute__((ext_vector_type(8))) short short8;   // 8 bf16 (4 VGPRs)
typedef __attribute__((ext_vector_type(4))) float f32x4;
typedef __attribute__((ext_vector_type(4))) unsigned uint4v;
typedef __attribute__((ext_vector_type(2))) unsigned uint2v;

// ---------------- fused bucketing kernel (single block; unchanged control) ----

__global__ __launch_bounds__(1024) void prep_k(const int* __restrict__ ind,
                                               int* __restrict__ rows,
                                               int* __restrict__ offsets) {
  __shared__ int hist[NEXP];
  __shared__ int scan[NEXP];
  __shared__ int cur[NEXP];
  int t = threadIdx.x;
  if (t < NEXP) hist[t] = 0;
  __syncthreads();
  for (int n = t; n < NROWS; n += 1024) atomicAdd(&hist[ind[n]], 1);
  __syncthreads();
  if (t < NEXP) scan[t] = hist[t];
  __syncthreads();
  for (int d = 1; d < NEXP; d <<= 1) {
    int v = (t < NEXP && t >= d) ? scan[t - d] : 0;
    __syncthreads();
    if (t < NEXP) scan[t] += v;
    __syncthreads();
  }
  if (t < NEXP) {
    int exc = scan[t] - hist[t];
    offsets[t] = exc;
    cur[t] = exc;
    if (t == NEXP - 1) offsets[NEXP] = scan[t];
  }
  __syncthreads();
  for (int n = t; n < NROWS; n += 1024) {
    int p = atomicAdd(&cur[ind[n]], 1);
    rows[p] = n;
  }
}

// ---------------- helpers ----------------

// fp32 -> bf16 round-to-nearest-even, manual bit twiddling (no non-trivially-
// copyable HIP types involved).
__device__ __forceinline__ unsigned bf16_rn(float f) {
  unsigned u = __builtin_bit_cast(unsigned, f);
  unsigned r = 0x7fffu + ((u >> 16) & 1u);
  return (u + r) >> 16;
}

__device__ __forceinline__ unsigned pk2(float a, float b) {
  return bf16_rn(a) | (bf16_rn(b) << 16);
}

__device__ __forceinline__ short8 cvt8(f32x4 w0, f32x4 w1) {
  uint4v u;
  u.x = pk2(w0.x, w0.y);
  u.y = pk2(w0.z, w0.w);
  u.z = pk2(w1.x, w1.y);
  u.w = pk2(w1.z, w1.w);
  return __builtin_bit_cast(short8, u);
}

__device__ __forceinline__ float fast_tanh(float v) {
  float e = __expf(2.f * v);
  return 1.f - 2.f * __builtin_amdgcn_rcpf(e + 1.f);
}

// One layer as MFMA 16x16x32 bf16, neurons on M, data rows on N.
// Wp: weight base for this wave's neuron range (row-major, K floats/row).
// bp: bias base for this wave's neuron range.
// Hin: LDS activations, row-major [64][HP] bf16, cols 0..K-1 valid.
// acc[mt][nt]: D frag for neuron-tile mt, row-tile nt.
template <int K, int NMT>
__device__ __forceinline__ void layer_mm(const float* __restrict__ Wp,
                                         const float* __restrict__ bp,
                                         const unsigned short* Hin,
                                         int l15, int q, f32x4 (&acc)[NMT][4]) {
#pragma unroll
  for (int mt = 0; mt < NMT; mt++) {
    f32x4 bv = *(const f32x4*)(bp + mt * 16 + q * 4);
#pragma unroll
    for (int nt = 0; nt < 4; nt++) acc[mt][nt] = bv;
  }
  const float* wr[NMT];
#pragma unroll
  for (int mt = 0; mt < NMT; mt++)
    wr[mt] = Wp + (size_t)(mt * 16 + l15) * K + q * 8;

#pragma unroll 2
  for (int ks = 0; ks < K / 32; ks++) {
    short8 bfr[4];
#pragma unroll
    for (int nt = 0; nt < 4; nt++)
      bfr[nt] = *(const short8*)&Hin[(nt * 16 + l15) * HP + ks * 32 + q * 8];
#pragma unroll
    for (int mt = 0; mt < NMT; mt++) {
      f32x4 w0 = *(const f32x4*)(wr[mt] + ks * 32);
      f32x4 w1 = *(const f32x4*)(wr[mt] + ks * 32 + 4);
      short8 a = cvt8(w0, w1);
#pragma unroll
      for (int nt = 0; nt < 4; nt++)
        acc[mt][nt] =
            __builtin_amdgcn_mfma_f32_16x16x32_bf16(a, bfr[nt], acc[mt][nt], 0, 0, 0);
    }
  }
}

// tanh + pack + store h-frags: frag (mt,nt) -> H[row nt*16+l15][neurons w*64+mt*16+q*4 ..+3]
__device__ __forceinline__ void write_h(f32x4 (&acc)[4][4], unsigned short* H,
                                        int w, int l15, int q) {
#pragma unroll
  for (int mt = 0; mt < 4; mt++)
#pragma unroll
    for (int nt = 0; nt < 4; nt++) {
      uint2v v;
      v.x = pk2(fast_tanh(acc[mt][nt].x), fast_tanh(acc[mt][nt].y));
      v.y = pk2(fast_tanh(acc[mt][nt].z), fast_tanh(acc[mt][nt].w));
      *(uint2v*)&H[(nt * 16 + l15) * HP + w * 64 + mt * 16 + q * 4] = v;
    }
}

// ---------------- main MLP kernel ----------------

__global__ __launch_bounds__(256, 2) void mlp_k(
    const float* __restrict__ x,
    const float* __restrict__ W1, const float* __restrict__ b1,
    const float* __restrict__ W2, const float* __restrict__ b2,
    const float* __restrict__ Wl, const float* __restrict__ bl,
    const int* __restrict__ rows, const int* __restrict__ offsets,
    float* __restrict__ out) {
  __shared__ __align__(16) unsigned short H[MT * HP];  // 33792 B

  const int t = threadIdx.x;
  const int w = t >> 6;          // wave 0..3
  const int l15 = t & 15;
  const int q = (t >> 4) & 3;    // quad within wave
  const int e = blockIdx.x >> 1;
  const int j = blockIdx.x & 1;
  const int beg = offsets[e];
  const int cnt = offsets[e + 1] - beg;

  const float* W1e = W1 + (size_t)e * HID * IN_DIM + (size_t)(w * 64) * IN_DIM;
  const float* W2e = W2 + (size_t)e * HID * HID + (size_t)(w * 64) * HID;
  const float* Wle = Wl + (size_t)e * OUT_DIM * HID + (size_t)(w * 16) * HID;
  const float* b1e = b1 + e * HID + w * 64;
  const float* b2e = b2 + e * HID + w * 64;
  const float* ble = bl + e * OUT_DIM + w * 16;

  const int sm = t >> 2;             // x-staging: row
  const int sc = (t & 3) * 16;       // x-staging: col base

  for (int mt0 = j * MT; mt0 < cnt; mt0 += 2 * MT) {
    __syncthreads();  // prev tile's l3 reads done before x-stage overwrites H
    // ---- stage x tile (fp32 global -> bf16 LDS cols 0..63), zero-pad tail rows
    {
      int gm = mt0 + sm;
      bool val = gm < cnt;
      int r = val ? rows[beg + gm] : 0;
      const float* xr = x + (size_t)r * IN_DIM + sc;
      uint4v u0, u1;
      if (val) {
        f32x4 a0 = *(const f32x4*)(xr);
        f32x4 a1 = *(const f32x4*)(xr + 4);
        f32x4 a2 = *(const f32x4*)(xr + 8);
        f32x4 a3 = *(const f32x4*)(xr + 12);
        u0.x = pk2(a0.x, a0.y); u0.y = pk2(a0.z, a0.w);
        u0.z = pk2(a1.x, a1.y); u0.w = pk2(a1.z, a1.w);
        u1.x = pk2(a2.x, a2.y); u1.y = pk2(a2.z, a2.w);
        u1.z = pk2(a3.x, a3.y); u1.w = pk2(a3.z, a3.w);
      } else {
        u0 = (uint4v){0, 0, 0, 0};
        u1 = (uint4v){0, 0, 0, 0};
      }
      *(uint4v*)&H[sm * HP + sc] = u0;
      *(uint4v*)&H[sm * HP + sc + 8] = u1;
    }
    __syncthreads();

    // ---- layer1: x(K=64) -> h1(256 neurons), tanh
    {
      f32x4 acc[4][4];
      layer_mm<IN_DIM, 4>(W1e, b1e, H, l15, q, acc);
      __syncthreads();  // all x reads done before h1 writes clobber H
      write_h(acc, H, w, l15, q);
    }
    __syncthreads();

    // ---- layer2: h1(K=256) -> h2(256), tanh (in-place region)
    {
      f32x4 acc[4][4];
      layer_mm<HID, 4>(W2e, b2e, H, l15, q, acc);
      __syncthreads();  // all h1 reads done before h2 writes
      write_h(acc, H, w, l15, q);
    }
    __syncthreads();

    // ---- layer3: h2(K=256) -> out (64 neurons); wave w owns neurons w*16..+15
    {
      f32x4 acc[1][4];
      layer_mm<HID, 1>(Wle, ble, H, l15, q, acc);
#pragma unroll
      for (int nt = 0; nt < 4; nt++) {
        int gm = mt0 + nt * 16 + l15;
        if (gm < cnt) {
          int r = rows[beg + gm];
          *(f32x4*)(out + (size_t)r * OUT_DIM + w * 16 + q * 4) = acc[0][nt];
        }
      }
    }
  }
}

// ---------------- launcher ----------------

extern "C" void kernel_launch(void* const* d_in, const int* in_sizes, int n_in,
                              void* d_out, int out_size, void* d_ws, size_t ws_size,
                              hipStream_t stream) {
  const float* x   = (const float*)d_in[0];
  const int*   ind = (const int*)d_in[1];
  const float* W1  = (const float*)d_in[2];
  const float* b1  = (const float*)d_in[3];
  const float* W2  = (const float*)d_in[4];
  const float* b2  = (const float*)d_in[5];
  const float* Wl  = (const float*)d_in[6];
  const float* bl  = (const float*)d_in[7];
  float* out = (float*)d_out;

  int* offsets = (int*)d_ws;        // 257 ints
  int* rows    = (int*)d_ws + 260;  // 16384 ints

  prep_k<<<1, 1024, 0, stream>>>(ind, rows, offsets);
  mlp_k<<<NEXP * 2, 256, 0, stream>>>(x, W1, b1, W2, b2, Wl, bl, rows, offsets, out);
}